// Round 1
// baseline (1042.285 us; speedup 1.0000x reference)
//
#include <hip/hip_runtime.h>

#define BEVW 432
#define BEVH 496
#define NCELL (BEVW*BEVH)      // 214272
#define NVOX  40000
#define EPSB  1e-5f

// ---------------- workspace layout (bytes) ----------------
// 0        : int nact                (zeroed)
// 256      : int cnt[NCELL]          (zeroed)          857088
// 857600   : int list[NCELL*16]                        13713408
// 14571008 : float voxelwise[NVOX*64]                  10240000
// 24811008 : int act[NVOX]                             160000
// 24971008 : float x17g[NVOX*128]                      20480000
// 45451008 : float fold[1168]
// 45455680 : float w4t[4096]
// total ~45.5 MB

__device__ __forceinline__ float mishf(float y) {
    float e = __expf(fminf(y, 40.f));
    float n = e * (e + 2.f);
    return y * n * __builtin_amdgcn_rcpf(n + 2.f);
}

// fold layout (floats):
// vfe1: s@0  t@8   | vfe2: s@16 t@48 | vfe3: s@80 t@144 | vfe4: s@208 t@272
// bfe3: s@336 t@464 | bfe1: s@592 t@848 | bfe2: s@1104 t@1136
__global__ __launch_bounds__(256) void setup_kernel(
    const float* __restrict__ vbn1, const float* __restrict__ vbn2,
    const float* __restrict__ vbn3, const float* __restrict__ vbn4,
    const float* __restrict__ bbn1, const float* __restrict__ bbn2,
    const float* __restrict__ bbn3, const float* __restrict__ W4,
    float* __restrict__ fold, float* __restrict__ w4t)
{
    int tid = threadIdx.x;
    if (tid < 8)  { float s = vbn1[tid]/sqrtf(vbn1[24+tid]+EPSB);  fold[tid]      = s; fold[8+tid]   = vbn1[8+tid]  - vbn1[16+tid]*s; }
    if (tid < 32) { float s = vbn2[tid]/sqrtf(vbn2[96+tid]+EPSB);  fold[16+tid]   = s; fold[48+tid]  = vbn2[32+tid] - vbn2[64+tid]*s; }
    if (tid < 64) { float s = vbn3[tid]/sqrtf(vbn3[192+tid]+EPSB); fold[80+tid]   = s; fold[144+tid] = vbn3[64+tid] - vbn3[128+tid]*s; }
    if (tid < 64) { float s = vbn4[tid]/sqrtf(vbn4[192+tid]+EPSB); fold[208+tid]  = s; fold[272+tid] = vbn4[64+tid] - vbn4[128+tid]*s; }
    if (tid < 128){ float s = bbn3[tid]/sqrtf(bbn3[384+tid]+EPSB); fold[336+tid]  = s; fold[464+tid] = bbn3[128+tid]- bbn3[256+tid]*s; }
    { // bfe1_bn [16][4][16]
        int g = tid >> 4, q = tid & 15;
        const float* b = bbn1 + g*64;
        float s = b[q]/sqrtf(b[48+q]+EPSB);
        fold[592+tid] = s; fold[848+tid] = b[16+q] - b[32+q]*s;
    }
    if (tid < 32) { // bfe2_bn [16][4][2]
        int g = tid >> 1, c = tid & 1;
        const float* b = bbn2 + g*8;
        float s = b[c]/sqrtf(b[6+c]+EPSB);
        fold[1104+tid] = s; fold[1136+tid] = b[2+c] - b[4+c]*s;
    }
    for (int i = tid; i < 4096; i += 256) { int o = i >> 6, c = i & 63; w4t[c*64+o] = W4[i]; }
}

// ---------------- VFE: 8 voxels / 256-thread block, lane=point ----------------
__global__ __launch_bounds__(256) void vfe_kernel(
    const float* __restrict__ feat, const int* __restrict__ coors,
    const int* __restrict__ nvx,
    const float* __restrict__ W1, const float* __restrict__ W2,
    const float* __restrict__ W3, const float* __restrict__ W4T,
    const float* __restrict__ fold,
    float* __restrict__ voxelwise, int* __restrict__ cnt,
    int* __restrict__ list, int* __restrict__ nact, int* __restrict__ act)
{
    int tid = threadIdx.x;
    int v = blockIdx.x * 8 + (tid >> 5);
    int t = tid & 31;

    const float* fp = feat + (v*32 + t)*8;
    float4 fa = *(const float4*)fp;
    float4 fb = *(const float4*)(fp+4);
    float f0[8] = {fa.x, fa.y, fa.z, fa.w, fb.x, fb.y, fb.z, fb.w};

    int numv = nvx[v];
    float maskf = (t < numv) ? 1.f : 0.f;

    // fe1 (8->8) + maxpool -> x1[16]
    float x1[16];
#pragma unroll
    for (int o = 0; o < 8; o++) {
        float y = 0.f;
#pragma unroll
        for (int c = 0; c < 8; c++) y += f0[c] * W1[o*8+c];
        y = y * fold[0+o] + fold[8+o];
        x1[o] = mishf(y);
    }
#pragma unroll
    for (int o = 0; o < 8; o++) {
        float a = x1[o];
#pragma unroll
        for (int m = 16; m >= 1; m >>= 1) a = fmaxf(a, __shfl_xor(a, m));
        x1[8+o] = a;
    }

    // fe2 (16->32) + maxpool -> x2[64], masked
    float x2[64];
#pragma unroll
    for (int o = 0; o < 32; o++) {
        float y = 0.f;
#pragma unroll
        for (int c = 0; c < 16; c++) y += x1[c] * W2[o*16+c];
        y = y * fold[16+o] + fold[48+o];
        x2[o] = mishf(y);
    }
#pragma unroll
    for (int o = 0; o < 32; o++) {
        float a = x2[o];
#pragma unroll
        for (int m = 16; m >= 1; m >>= 1) a = fmaxf(a, __shfl_xor(a, m));
        x2[32+o] = a * maskf;
        x2[o]   *= maskf;
    }

    // fe3 (64->64) and fe4 accumulated incrementally via W4T
    float acc4[64];
#pragma unroll
    for (int q = 0; q < 64; q++) acc4[q] = 0.f;
#pragma unroll 2
    for (int o = 0; o < 64; o++) {
        const float* w3r = W3 + o*64;
        float y = 0.f;
#pragma unroll
        for (int c = 0; c < 64; c++) y += x2[c] * w3r[c];
        y = y * fold[80+o] + fold[144+o];
        float x3 = mishf(y);
        const float* w4r = W4T + o*64;
#pragma unroll
        for (int q = 0; q < 64; q++) acc4[q] += x3 * w4r[q];
    }

    // bn4 + mish, residual, max over points
#pragma unroll
    for (int q = 0; q < 64; q++) {
        float y = acc4[q] * fold[208+q] + fold[272+q];
        y = mishf(y) * maskf + x2[q];
#pragma unroll
        for (int m = 16; m >= 1; m >>= 1) y = fmaxf(y, __shfl_xor(y, m));
        x2[q] = y;   // voxel max, identical in all 32 lanes of the group
    }

    if (t == 0) {
        float4* dst = (float4*)(voxelwise + v*64);
#pragma unroll
        for (int q = 0; q < 16; q++)
            dst[q] = make_float4(x2[4*q], x2[4*q+1], x2[4*q+2], x2[4*q+3]);
        int cell = coors[v*2] * BEVW + coors[v*2+1];
        int pos = atomicAdd(&cnt[cell], 1);
        if (pos < 16) list[cell*16 + pos] = v;
        if (pos == 0) { int k = atomicAdd(nact, 1); act[k] = cell; }
    }
}

// ---------------- BFE front (bfe1+bfe2): 1 wave = 1 active cell ----------------
__global__ __launch_bounds__(256) void bfe_front(
    const int* __restrict__ nact, const int* __restrict__ act,
    const int* __restrict__ cnt, const int* __restrict__ list,
    const float* __restrict__ voxelwise,
    const float* __restrict__ W1g, const float* __restrict__ W2g,
    const float* __restrict__ fold, float* __restrict__ x17g)
{
    __shared__ float W1L[16*257];   // [g][q*16+p], stride 257 -> conflict-free
    __shared__ float W2L[16*33];    // [g][c*16+p], stride 33
    for (int i = threadIdx.x; i < 4096; i += 256) W1L[(i>>8)*257 + (i&255)] = W1g[i];
    for (int i = threadIdx.x; i < 512;  i += 256) W2L[(i>>5)*33  + (i&31)]  = W2g[i];
    __syncthreads();

    int n_act = *nact;
    int aidx = blockIdx.x * 4 + (threadIdx.x >> 6);
    if (aidx >= n_act) return;                   // wave-uniform

    int lane = threadIdx.x & 63;
    int g = lane >> 2, ii = lane & 3;
    int cell = act[aidx];
    int numv = min(cnt[cell], 16);

    // sort kept voxel indices ascending (slot order = original-index order)
    int myidx = (lane < numv) ? list[cell*16 + lane] : (0x40000000 + lane);
    int rank = 0;
    for (int j = 0; j < numv; j++) { int vj = __shfl(myidx, j); rank += (vj < myidx) ? 1 : 0; }
    if (lane >= numv) rank = lane;
    int sorted = __builtin_amdgcn_ds_permute(rank << 2, myidx);

    // bfe1: y[q] = sum_p val[p]*W1[g][q][p]  (val[p]=0 for p>=numv)
    float y[16];
#pragma unroll
    for (int q = 0; q < 16; q++) y[q] = 0.f;
    for (int p = 0; p < numv; p++) {
        int sv = __shfl(sorted, p);
        float val = voxelwise[sv*64 + lane];
        const float* w = &W1L[g*257 + p];
#pragma unroll
        for (int q = 0; q < 16; q++) y[q] += val * w[q*16];
    }
#pragma unroll
    for (int q = 0; q < 16; q++) {
        float yy = y[q] * fold[592 + g*16 + q] + fold[848 + g*16 + q];
        yy = mishf(yy);
        y[q] = (q < numv) ? yy : 0.f;
    }

    // bfe2: z[c] = sum_p y[p]*W2[g][c][p]
    float z0 = 0.f, z1 = 0.f;
#pragma unroll
    for (int p = 0; p < 16; p++) {
        z0 += y[p] * W2L[g*33 + p];
        z1 += y[p] * W2L[g*33 + 16 + p];
    }
    z0 = mishf(z0 * fold[1104 + g*2 + 0] + fold[1136 + g*2 + 0]);
    z1 = mishf(z1 * fold[1104 + g*2 + 1] + fold[1136 + g*2 + 1]);

    int k0 = ii*32 + g*2;                        // x17 index = i*32 + g*2 + c
    *(float2*)(x17g + aidx*128 + k0) = make_float2(z0, z1);
}

// ---------------- bfe3 pass 1: x18 = fe(x17 @ W3.T), in-place ----------------
__global__ __launch_bounds__(256) void bfe3_pass(
    const int* __restrict__ nactp, const float* __restrict__ W3,
    const float* __restrict__ fold, float* __restrict__ io)
{
    int tid = blockIdx.x * 256 + threadIdx.x;
    if (tid >= *nactp) return;
    const float4* xin = (const float4*)(io + tid*128);
    float x[128];
#pragma unroll
    for (int k = 0; k < 32; k++) {
        float4 a = xin[k];
        x[4*k] = a.x; x[4*k+1] = a.y; x[4*k+2] = a.z; x[4*k+3] = a.w;
    }
#pragma unroll 2
    for (int o = 0; o < 128; o++) {
        const float* wr = W3 + o*128;
        float y = 0.f;
#pragma unroll
        for (int k = 0; k < 128; k++) y += x[k] * wr[k];
        y = y * fold[336+o] + fold[464+o];
        io[tid*128 + o] = mishf(y);
    }
}

// ---------------- bfe3 pass 2: x19 + scatter to out[c][w][h] ----------------
__global__ __launch_bounds__(256) void bfe3_out(
    const int* __restrict__ nactp, const int* __restrict__ act,
    const float* __restrict__ W3, const float* __restrict__ fold,
    const float* __restrict__ x18g, float* __restrict__ out)
{
    int tid = blockIdx.x * 256 + threadIdx.x;
    if (tid >= *nactp) return;
    const float4* xin = (const float4*)(x18g + tid*128);
    float x[128];
#pragma unroll
    for (int k = 0; k < 32; k++) {
        float4 a = xin[k];
        x[4*k] = a.x; x[4*k+1] = a.y; x[4*k+2] = a.z; x[4*k+3] = a.w;
    }
    int cell = act[tid];
    int h = cell / BEVW;
    int w = cell - h * BEVW;
    float* op = out + w*BEVH + h;
#pragma unroll 2
    for (int o = 0; o < 128; o++) {
        const float* wr = W3 + o*128;
        float y = 0.f;
#pragma unroll
        for (int k = 0; k < 128; k++) y += x[k] * wr[k];
        y = y * fold[336+o] + fold[464+o];
        op[o * NCELL] = mishf(y);
    }
}

extern "C" void kernel_launch(void* const* d_in, const int* in_sizes, int n_in,
                              void* d_out, int out_size, void* d_ws, size_t ws_size,
                              hipStream_t stream) {
    const float* features = (const float*)d_in[0];
    const int*   coors    = (const int*)d_in[1];
    const int*   num_vox  = (const int*)d_in[2];
    const float* vfe1_W   = (const float*)d_in[3];
    const float* vfe1_bn  = (const float*)d_in[4];
    const float* vfe2_W   = (const float*)d_in[5];
    const float* vfe2_bn  = (const float*)d_in[6];
    const float* vfe3_W   = (const float*)d_in[7];
    const float* vfe3_bn  = (const float*)d_in[8];
    const float* vfe4_W   = (const float*)d_in[9];
    const float* vfe4_bn  = (const float*)d_in[10];
    const float* bfe1_W   = (const float*)d_in[11];
    const float* bfe1_bn  = (const float*)d_in[12];
    const float* bfe2_W   = (const float*)d_in[13];
    const float* bfe2_bn  = (const float*)d_in[14];
    const float* bfe3_W   = (const float*)d_in[15];
    const float* bfe3_bn  = (const float*)d_in[16];
    float* out = (float*)d_out;

    char* ws = (char*)d_ws;
    int*   nact      = (int*)ws;
    int*   cnt       = (int*)(ws + 256);
    int*   list      = (int*)(ws + 857600);
    float* voxelwise = (float*)(ws + 14571008);
    int*   act       = (int*)(ws + 24811008);
    float* x17g      = (float*)(ws + 24971008);
    float* fold      = (float*)(ws + 45451008);
    float* w4t       = (float*)(ws + 45455680);

    hipMemsetAsync(ws, 0, 857600, stream);                       // nact + cnt
    hipMemsetAsync(d_out, 0, (size_t)out_size * sizeof(float), stream);

    setup_kernel<<<1, 256, 0, stream>>>(vfe1_bn, vfe2_bn, vfe3_bn, vfe4_bn,
                                        bfe1_bn, bfe2_bn, bfe3_bn, vfe4_W,
                                        fold, w4t);
    vfe_kernel<<<NVOX/8, 256, 0, stream>>>(features, coors, num_vox,
                                           vfe1_W, vfe2_W, vfe3_W, w4t, fold,
                                           voxelwise, cnt, list, nact, act);
    bfe_front<<<NVOX/4, 256, 0, stream>>>(nact, act, cnt, list, voxelwise,
                                          bfe1_W, bfe2_W, fold, x17g);
    bfe3_pass<<<(NVOX+255)/256, 256, 0, stream>>>(nact, bfe3_W, fold, x17g);
    bfe3_out<<<(NVOX+255)/256, 256, 0, stream>>>(nact, act, bfe3_W, fold, x17g, out);
}